// Round 6
// baseline (72.240 us; speedup 1.0000x reference)
//
#include <hip/hip_runtime.h>
#include <hip/hip_bf16.h>
#include <math.h>

#define Bn  16
#define Ln  256
#define Wn  4
#define Hn  128
#define Nn  259          // L + W - 1
#define NPAD 320         // padded rows per (arr,b); rows >= Nn are zeros
#define EPSF 1e-6f

typedef float f32x4 __attribute__((ext_vector_type(4)));
typedef short s16x8 __attribute__((ext_vector_type(8)));

// bf16 bits of x1 (index 0) and x2 (index 1), zero-padded to NPAD rows, and
// per-row norms of the ROUNDED (bf16) values — bit-consistent with the
// mfma(af,af) Gram norms of the harness-proven round-1 kernel. Fully
// rewritten (incl. pad zeros) every iteration; read across the kernel
// boundary (release/acquire coherence proven rounds 0/1).
__device__ unsigned short g_c[2][Bn][NPAD][Hn];
__device__ float          g_nrm[2][Bn][NPAD];

__device__ __forceinline__ unsigned short bfb(float x) {
    union { __hip_bfloat16 h; unsigned short u; } t;
    t.h = __float2bfloat16(x);
    return t.u;
}
__device__ __forceinline__ float bf2f(unsigned short u) {
    union { unsigned int i; float f; } t;
    t.i = (unsigned int)u << 16;
    return t.f;
}

// One-shot fp32->bf16 conversion + row norms (of the rounded values).
// Grid (2, Bn, NPAD/8): block = 8 rows of one (arr,b). Thread = one float4:
// row = tid>>5, c4 = tid&31 -> block reads 4KB contiguous, writes 2KB.
__global__ __launch_bounds__(256) void conv(const float* __restrict__ x1,
                                            const float* __restrict__ x2) {
    const int arr = blockIdx.x, b = blockIdx.y;
    const int row = blockIdx.z * 8 + (threadIdx.x >> 5);
    const int c4  = threadIdx.x & 31;
    const float* srcb = (arr ? x2 : x1) + (size_t)b * Nn * Hn;

    float4 v = make_float4(0.f, 0.f, 0.f, 0.f);
    if (row < Nn) v = ((const float4*)(srcb + row * Hn))[c4];

    const unsigned short u0 = bfb(v.x), u1 = bfb(v.y), u2 = bfb(v.z), u3 = bfb(v.w);
    *((unsigned long long*)&g_c[arr][b][row][c4 * 4]) =
        (unsigned long long)u0        | ((unsigned long long)u1 << 16) |
        ((unsigned long long)u2 << 32) | ((unsigned long long)u3 << 48);

    // norm of rounded values (matches bf16-MFMA Gram numerics)
    const float r0 = bf2f(u0), r1 = bf2f(u1), r2 = bf2f(u2), r3 = bf2f(u3);
    float ss = r0 * r0 + r1 * r1 + r2 * r2 + r3 * r3;
    #pragma unroll
    for (int off = 16; off; off >>= 1) ss += __shfl_down(ss, off, 32);
    if (c4 == 0) g_nrm[arr][b][row] = ss;     // rows >= Nn get 0 (v = zeros)
}

// Fused attention-sum + weighted pool. 1024 independent blocks (proven wp
// indexing: blk<512 -> x1 half). Block (half,b,8-l-chunk) computes the 11
// attention sums a[l0..l0+10] it needs DIRECTLY (no cross-block deps):
//   dist is symmetric => both halves are "sum over all rows of the OTHER
//   array": queries = pooled array rows l0..l0+10, keys = other array (259).
// MFMA frags loaded straight from global bf16 (lane mapping carried verbatim
// from the harness-verified round-1 kernel):
//   A-frag (keys, i): lane holds A[m=rsel][k=q*8+..]; B-frag (queries, j) same;
//   C/D: col(j)=rsel, row(i)=q*4+reg.
__global__ __launch_bounds__(256) void attwp(const float* __restrict__ x1,
                                             const float* __restrict__ x2,
                                             float* __restrict__ out) {
    __shared__ float nks[NPAD];
    __shared__ float awave[4][16];
    __shared__ float a_s[11];

    const int blk = blockIdx.x;
    const bool second = blk >= 512;
    const int eb = (second ? blk - 512 : blk) * 256;
    const int b  = eb >> 13;
    const int l0 = (eb & 8191) >> 5;
    const int tid = threadIdx.x;

    const unsigned short* qc = &g_c[second ? 1 : 0][b][0][0];   // queries = pooled arr
    const unsigned short* kc = &g_c[second ? 0 : 1][b][0][0];   // keys = other arr
    const float* nq = &g_nrm[second ? 1 : 0][b][0];
    const float* nk = &g_nrm[second ? 0 : 1][b][0];

    if (tid < NPAD / 4) ((f32x4*)nks)[tid] = ((const f32x4*)nk)[tid];

    const int w = tid >> 6, lane = tid & 63;
    const int rsel = lane & 15, q = lane >> 4;

    // query B-frags: rows l0+rsel (<= 263 < NPAD, pad rows are zeros)
    const unsigned short* qrow = qc + (l0 + rsel) * Hn + q * 8;
    const s16x8 bq0 = *((const s16x8*)(qrow));
    const s16x8 bq1 = *((const s16x8*)(qrow + 32));
    const s16x8 bq2 = *((const s16x8*)(qrow + 64));
    const s16x8 bq3 = *((const s16x8*)(qrow + 96));
    const float nqv = nq[l0 + rsel];
    __syncthreads();                          // nks staged

    // wave w streams key i-tiles w, w+4, ... (17 tiles over 259+pad rows)
    float psum = 0.f;
    const unsigned short* krow = kc + rsel * Hn + q * 8;
    for (int tile = w; tile < 17; tile += 4) {
        const unsigned short* kr = krow + tile * 16 * Hn;
        f32x4 acc = {0, 0, 0, 0};
        acc = __builtin_amdgcn_mfma_f32_16x16x32_bf16(*((const s16x8*)(kr)),      bq0, acc, 0, 0, 0);
        acc = __builtin_amdgcn_mfma_f32_16x16x32_bf16(*((const s16x8*)(kr + 32)), bq1, acc, 0, 0, 0);
        acc = __builtin_amdgcn_mfma_f32_16x16x32_bf16(*((const s16x8*)(kr + 64)), bq2, acc, 0, 0, 0);
        acc = __builtin_amdgcn_mfma_f32_16x16x32_bf16(*((const s16x8*)(kr + 96)), bq3, acc, 0, 0, 0);
        const int ibase = tile * 16 + q * 4;
        const f32x4 nkv = *((const f32x4*)&nks[ibase]);
        #pragma unroll
        for (int reg = 0; reg < 4; ++reg) {
            const float e   = fmaf(-2.f, acc[reg], nkv[reg] + nqv + EPSF);
            const float att = __builtin_amdgcn_rcpf(__builtin_amdgcn_sqrtf(e) + 1.f);
            psum += (ibase + reg < Nn) ? att : 0.f;   // mask pad keys (zeros != f-neutral)
        }
    }
    // reduce over q (i within tile-row-groups), then across waves
    psum += __shfl_xor(psum, 16);
    psum += __shfl_xor(psum, 32);
    if (lane < 16) awave[w][lane] = psum;
    __syncthreads();
    if (tid < 11)
        a_s[tid] = awave[0][tid] + awave[1][tid] + awave[2][tid] + awave[3][tid];
    __syncthreads();

    // ---- weighted pool (proven wp body; x = ORIGINAL fp32 array) ----
    const int PER = Bn * Ln * Hn / 4;         // 131072 float4 per output half
    const float* x = second ? x2 : x1;
    const int e  = eb + tid;
    const int l  = (e & 8191) >> 5;
    const int h4 = e & 31;
    const float4* xb = (const float4*)(x + (size_t)b * Nn * Hn);
    float4 accw = make_float4(0.f, 0.f, 0.f, 0.f);
    #pragma unroll
    for (int k = 0; k < Wn; ++k) {
        const float  av = a_s[l - l0 + k];
        const float4 xv = xb[(l + k) * (Hn / 4) + h4];
        accw.x += av * xv.x;
        accw.y += av * xv.y;
        accw.z += av * xv.z;
        accw.w += av * xv.w;
    }
    ((float4*)out)[(second ? PER : 0) + e] = accw;
}

extern "C" void kernel_launch(void* const* d_in, const int* in_sizes, int n_in,
                              void* d_out, int out_size, void* d_ws, size_t ws_size,
                              hipStream_t stream) {
    const float* x1 = (const float*)d_in[0];
    const float* x2 = (const float*)d_in[1];
    (void)d_ws; (void)ws_size;            // workspace intentionally unused

    conv<<<dim3(2, Bn, NPAD / 8), 256, 0, stream>>>(x1, x2);
    attwp<<<1024, 256, 0, stream>>>(x1, x2, (float*)d_out);
}

// Round 7
// 68.946 us; speedup vs baseline: 1.0478x; 1.0478x over previous
//
#include <hip/hip_runtime.h>
#include <hip/hip_bf16.h>
#include <math.h>

#define Bn  16
#define Ln  256
#define Wn  4
#define Hn  128
#define Nn  259          // L + W - 1
#define EPSF 1e-6f
#define PSTR 320         // padded per-(slice,batch) stride in partial arrays
#define X2AP_OFF (5 * Bn * PSTR)      // x1a_p size in floats

typedef float f32x4 __attribute__((ext_vector_type(4)));
typedef short s16x8 __attribute__((ext_vector_type(8)));

// Cross-kernel partial sums in a module-scope device global (200 KB); every
// slot is written by exactly one thread in att2 before the kernel boundary,
// then read by wp_kernel (boundary release/acquire gives coherence —
// harness-verified rounds 0/1). No poison/stale-state hazard.
__device__ float g_part[2 * X2AP_OFF];

__device__ __forceinline__ unsigned short bfb(float x) {
    union { __hip_bfloat16 h; unsigned short u; } t;
    t.h = __float2bfloat16(x);
    return t.u;
}

// Block: 64i x 64j att tile, batch b. fp32 -> bf16 conversion fused into LDS
// staging; row norms via mfma(a,a) Gram diagonal (no prep kernel, no atomics).
// Partial sums to private slices:
//   x1a_p[it][b][j] = sum over this block's 64 i   (5 it slices)
//   x2a_p[jt][b][i] = sum over this block's 64 j   (5 jt slices)
// A-frag: lane holds A[m=lane&15][k=(lane>>4)*8+j]; C/D: col=lane&15,
// row=(lane>>4)*4+reg  (HW-verified, learn_hip m89/m91/m120).
// NOTE (session history): 400 blocks / 4-wave staging is the measured best;
// 240-block 128x64 retile (1 blk/CU) regressed to 71.6 (occupancy loss during
// latency-bound staging), soft grid-barrier fusion regressed to 85-168,
// shared-conv restructure regressed to 72.2. Do not re-attempt without new
// counter evidence.
__global__ __launch_bounds__(256) void att2(const float* __restrict__ x1,
                                            const float* __restrict__ x2) {
    __shared__ unsigned short As[64 * 136];   // x2 rows; stride 136 -> 2-way banks (free)
    __shared__ unsigned short Bs[64 * 136];   // x1 rows
    __shared__ float n2s[64], n1s[64];
    __shared__ float colpart[4 * 64];

    const int it = blockIdx.x, jt = blockIdx.y, b = blockIdx.z;
    const int i0 = it * 64, j0 = jt * 64;
    const int tid = threadIdx.x;

    const float* __restrict__ x1b = x1 + (size_t)b * Nn * Hn;
    const float* __restrict__ x2b = x2 + (size_t)b * Nn * Hn;

    // stage both tiles: 8 iters x (one float4 per lane per tile), convert to bf16
    #pragma unroll
    for (int iter = 0; iter < 8; ++iter) {
        const int idx = iter * 256 + tid;
        const int r = idx >> 5, c4 = idx & 31;
        float4 va = make_float4(0.f, 0.f, 0.f, 0.f), vb = va;
        if (i0 + r < Nn) va = ((const float4*)(x2b + (i0 + r) * Hn))[c4];
        if (j0 + r < Nn) vb = ((const float4*)(x1b + (j0 + r) * Hn))[c4];
        const unsigned long long pa =
            (unsigned long long)bfb(va.x)        | ((unsigned long long)bfb(va.y) << 16) |
            ((unsigned long long)bfb(va.z) << 32) | ((unsigned long long)bfb(va.w) << 48);
        const unsigned long long pb =
            (unsigned long long)bfb(vb.x)        | ((unsigned long long)bfb(vb.y) << 16) |
            ((unsigned long long)bfb(vb.z) << 32) | ((unsigned long long)bfb(vb.w) << 48);
        *((unsigned long long*)&As[r * 136 + c4 * 4]) = pa;
        *((unsigned long long*)&Bs[r * 136 + c4 * 4]) = pb;
    }
    __syncthreads();

    const int w = tid >> 6, lane = tid & 63;
    const int rsel = lane & 15, q = lane >> 4;

    f32x4 acc[4] = {{0,0,0,0}, {0,0,0,0}, {0,0,0,0}, {0,0,0,0}};
    f32x4 accA = {0,0,0,0}, accB = {0,0,0,0};     // Gram accumulators for norms
    const unsigned short* arow  = &As[(w * 16 + rsel) * 136 + q * 8];
    const unsigned short* bnrow = &Bs[(w * 16 + rsel) * 136 + q * 8];
    const unsigned short* brow  = &Bs[rsel * 136 + q * 8];
    #pragma unroll
    for (int s = 0; s < 4; ++s) {                 // K-steps of 32
        const s16x8 af = *((const s16x8*)(arow + s * 32));
        const s16x8 bn = *((const s16x8*)(bnrow + s * 32));
        accA = __builtin_amdgcn_mfma_f32_16x16x32_bf16(af, af, accA, 0, 0, 0);
        accB = __builtin_amdgcn_mfma_f32_16x16x32_bf16(bn, bn, accB, 0, 0, 0);
        #pragma unroll
        for (int t = 0; t < 4; ++t) {             // j-tiles of 16
            const s16x8 bf = *((const s16x8*)(brow + t * 16 * 136 + s * 32));
            acc[t] = __builtin_amdgcn_mfma_f32_16x16x32_bf16(af, bf, acc[t], 0, 0, 0);
        }
    }

    // Gram diagonal d lives at lane(col=d, row=d): q==d>>2, reg==d&3
    if (q == (rsel >> 2)) {
        n2s[w * 16 + rsel] = accA[rsel & 3];
        n1s[w * 16 + rsel] = accB[rsel & 3];
    }
    __syncthreads();   // n1s is read across waves below

    float rowacc[4] = {0.f, 0.f, 0.f, 0.f};
    #pragma unroll
    for (int t = 0; t < 4; ++t) {
        const int   j   = j0 + t * 16 + rsel;
        const bool  jv  = (j < Nn);
        const float n1v = n1s[t * 16 + rsel];
        float cp = 0.f;
        #pragma unroll
        for (int reg = 0; reg < 4; ++reg) {
            const int   i   = i0 + w * 16 + q * 4 + reg;
            const float e   = fmaf(-2.f, acc[t][reg], n2s[w * 16 + q * 4 + reg] + n1v + EPSF);
            // approx sqrt+rcp (~1 ulp each): error ~1e-6 relative, well inside tol
            const float att = ((i < Nn) && jv)
                ? __builtin_amdgcn_rcpf(__builtin_amdgcn_sqrtf(e) + 1.f) : 0.f;
            rowacc[reg] += att;
            cp          += att;
        }
        cp += __shfl_xor(cp, 16);                 // reduce over q (wave's 16 i)
        cp += __shfl_xor(cp, 32);
        if (q == 0) colpart[w * 64 + t * 16 + rsel] = cp;
    }
    // row sums (this block's 64 j): each i owned by exactly one wave -> plain store
    #pragma unroll
    for (int reg = 0; reg < 4; ++reg) {
        float rs = rowacc[reg];
        #pragma unroll
        for (int off = 8; off; off >>= 1) rs += __shfl_down(rs, off, 16);
        const int i = i0 + w * 16 + q * 4 + reg;
        if (rsel == 0 && i < Nn)
            g_part[X2AP_OFF + (jt * Bn + b) * PSTR + i] = rs;
    }
    __syncthreads();   // colpart complete
    if (tid < 64) {
        const int j = j0 + tid;
        if (j < Nn)
            g_part[(it * Bn + b) * PSTR + j] =
                colpart[tid] + colpart[64 + tid] + colpart[128 + tid] + colpart[192 + tid];
    }
}

// out[b,l,h] = sum_{k<4} x[b,l+k,h] * a[b,l+k], a = sum of 5 partial slices.
// Block covers 256 consecutive float4 = 8 l values of one (half,b); needs
// a[b, l0..l0+10] -> reduce the 5 partials once into LDS.
__global__ __launch_bounds__(256) void wp_kernel(const float* __restrict__ x1,
                                                 const float* __restrict__ x2,
                                                 float* __restrict__ out) {
    __shared__ float a_s[11];
    const int PER = Bn * Ln * Hn / 4;    // 131072 float4 per output half
    const int blk = blockIdx.x;
    const bool second = blk >= 512;
    const int eb = (second ? blk - 512 : blk) * 256;
    const int b  = eb >> 13;
    const int l0 = (eb & 8191) >> 5;

    const float* x = second ? x2 : x1;
    const float* p = g_part + (second ? X2AP_OFF : 0) + b * PSTR;
    if (threadIdx.x < 11) {
        const int j = l0 + threadIdx.x;          // <= 258, always written
        float s = 0.f;
        #pragma unroll
        for (int t = 0; t < 5; ++t) s += p[t * (Bn * PSTR) + j];
        a_s[threadIdx.x] = s;
    }
    __syncthreads();

    const int e  = eb + threadIdx.x;
    const int l  = (e & 8191) >> 5;
    const int h4 = e & 31;
    const float4* xb = (const float4*)(x + (size_t)b * Nn * Hn);
    float4 acc = make_float4(0.f, 0.f, 0.f, 0.f);
    #pragma unroll
    for (int k = 0; k < Wn; ++k) {
        const float  av = a_s[l - l0 + k];
        const float4 xv = xb[(l + k) * (Hn / 4) + h4];
        acc.x += av * xv.x;
        acc.y += av * xv.y;
        acc.z += av * xv.z;
        acc.w += av * xv.w;
    }
    ((float4*)out)[(second ? PER : 0) + e] = acc;
}

extern "C" void kernel_launch(void* const* d_in, const int* in_sizes, int n_in,
                              void* d_out, int out_size, void* d_ws, size_t ws_size,
                              hipStream_t stream) {
    const float* x1 = (const float*)d_in[0];
    const float* x2 = (const float*)d_in[1];
    (void)d_ws; (void)ws_size;            // workspace intentionally unused

    dim3 gridA(5, 5, Bn);                 // 64x64 tiles over 259x259, 16 batches
    att2<<<gridA, 256, 0, stream>>>(x1, x2);

    wp_kernel<<<1024, 256, 0, stream>>>(x1, x2, (float*)d_out);
}